// Round 2
// baseline (297.285 us; speedup 1.0000x reference)
//
#include <hip/hip_runtime.h>

// QuaternionLinear as one 4096^3 bf16 GEMM (B^T layout).
// Round 2: 32x32x16 MFMA (17% fewer matrix-pipe cycles than 16x16x32),
// single fused conversion kernel.
// out[b][o*4+d] = sum_{i,c} x[b][i*4+c] * Wbig[o*4+d][i*4+c] + bias[o*4+d]
// Wbig rows (c order) per quaternion w=(r,i,j,k):
//   d=0: [+r, -i, -j, -k]
//   d=1: [+i, +r, +k, -j]
//   d=2: [+j, -k, +r, +i]
//   d=3: [+k, +j, -i, +r]

typedef __bf16 bf16x8 __attribute__((ext_vector_type(8)));
typedef float floatx16 __attribute__((ext_vector_type(16)));

constexpr int M = 4096;   // batch
constexpr int N = 4096;   // out_f * 4
constexpr int K = 4096;   // in_f * 4
constexpr int BM = 128, BN = 128, BK = 32;

constexpr int CVT_BLOCKS = (M * K / 8) / 256;        // 8192: x fp32 -> bf16
constexpr int EXP_BLOCKS = (1024 * 1024 / 2) / 256;  // 2048: w -> signed Wbig

// ---------- fused prep: x -> A (bf16), w -> Wbig (sign-expanded bf16) ----------
__global__ void prep_kernel(const float* __restrict__ x, const float* __restrict__ w,
                            __bf16* __restrict__ A, __bf16* __restrict__ Wb) {
    const int b = blockIdx.x;
    if (b < CVT_BLOCKS) {
        const size_t i = (size_t)b * 256 + threadIdx.x;   // 8 elems/thread
        const float4* xp = (const float4*)x;
        float4 a = xp[2 * i];
        float4 c = xp[2 * i + 1];
        bf16x8 v;
        v[0] = (__bf16)a.x; v[1] = (__bf16)a.y; v[2] = (__bf16)a.z; v[3] = (__bf16)a.w;
        v[4] = (__bf16)c.x; v[5] = (__bf16)c.y; v[6] = (__bf16)c.z; v[7] = (__bf16)c.w;
        *(bf16x8*)(A + 8 * i) = v;
    } else {
        const int idx = (b - CVT_BLOCKS) * 256 + threadIdx.x;  // quaternion PAIR index
        const int o  = idx >> 9;           // 512 pairs per output quaternion row
        const int ip = (idx & 511) * 2;    // first input-quaternion index
        float4 q0 = ((const float4*)w)[o * 1024 + ip];
        float4 q1 = ((const float4*)w)[o * 1024 + ip + 1];
        __bf16* base = Wb + (size_t)(o * 4) * K + ip * 4;
        bf16x8 r;
        // d=0: [+r,-i,-j,-k]
        r[0] = (__bf16)q0.x; r[1] = (__bf16)(-q0.y); r[2] = (__bf16)(-q0.z); r[3] = (__bf16)(-q0.w);
        r[4] = (__bf16)q1.x; r[5] = (__bf16)(-q1.y); r[6] = (__bf16)(-q1.z); r[7] = (__bf16)(-q1.w);
        *(bf16x8*)(base) = r;
        // d=1: [+i,+r,+k,-j]
        r[0] = (__bf16)q0.y; r[1] = (__bf16)q0.x; r[2] = (__bf16)q0.w; r[3] = (__bf16)(-q0.z);
        r[4] = (__bf16)q1.y; r[5] = (__bf16)q1.x; r[6] = (__bf16)q1.w; r[7] = (__bf16)(-q1.z);
        *(bf16x8*)(base + (size_t)K) = r;
        // d=2: [+j,-k,+r,+i]
        r[0] = (__bf16)q0.z; r[1] = (__bf16)(-q0.w); r[2] = (__bf16)q0.x; r[3] = (__bf16)q0.y;
        r[4] = (__bf16)q1.z; r[5] = (__bf16)(-q1.w); r[6] = (__bf16)q1.x; r[7] = (__bf16)q1.y;
        *(bf16x8*)(base + (size_t)2 * K) = r;
        // d=3: [+k,+j,-i,+r]
        r[0] = (__bf16)q0.w; r[1] = (__bf16)q0.z; r[2] = (__bf16)(-q0.y); r[3] = (__bf16)q0.x;
        r[4] = (__bf16)q1.w; r[5] = (__bf16)q1.z; r[6] = (__bf16)(-q1.y); r[7] = (__bf16)q1.x;
        *(bf16x8*)(base + (size_t)3 * K) = r;
    }
}

// ---------- async global->LDS, 16B per lane ----------
__device__ __forceinline__ void gload_lds16(const __bf16* g, __bf16* l) {
    __builtin_amdgcn_global_load_lds(
        (const __attribute__((address_space(1))) void*)g,
        (__attribute__((address_space(3))) void*)l, 16, 0, 0);
}

// ---------- GEMM: C[M][N] = A[M][K] * B[N][K]^T + bias[N], 32x32x16 MFMA ----------
__global__ void qgemm_kernel(const __bf16* __restrict__ A,
                             const __bf16* __restrict__ B,
                             const float* __restrict__ bias,
                             float* __restrict__ C) {
    __shared__ __bf16 As[BM][BK];
    __shared__ __bf16 Bs[BN][BK];

    const int tid  = threadIdx.x;
    const int wave = tid >> 6;
    const int lane = tid & 63;
    const int bm = blockIdx.y * BM;
    const int bn = blockIdx.x * BN;
    const int wm = (wave & 1) * 64;   // wave's 64x64 C-subtile origin
    const int wn = (wave >> 1) * 64;

    // staging: each global_load_lds issue covers 16 rows x 32 cols (64 lanes x 16B)
    const int ldrow = lane >> 2;
    const int ldcol = (lane & 3) * 8;

    const __bf16* ag0 = A + (size_t)(bm + wave * 16 + ldrow) * K + ldcol;
    const __bf16* ag1 = ag0 + (size_t)64 * K;
    const __bf16* bg0 = B + (size_t)(bn + wave * 16 + ldrow) * K + ldcol;
    const __bf16* bg1 = bg0 + (size_t)64 * K;

    __bf16* as0 = &As[wave * 16][0];        // wave-uniform base; HW adds lane*16B
    __bf16* as1 = &As[64 + wave * 16][0];
    __bf16* bs0 = &Bs[wave * 16][0];
    __bf16* bs1 = &Bs[64 + wave * 16][0];

    floatx16 acc[2][2] = {};

    const int fl = lane & 31;          // m (A) / n (B) index within 32
    const int fk = (lane >> 5) * 8;    // k offset within k-step of 16

    for (int k0 = 0; k0 < K; k0 += BK) {
        gload_lds16(ag0 + k0, as0);
        gload_lds16(ag1 + k0, as1);
        gload_lds16(bg0 + k0, bs0);
        gload_lds16(bg1 + k0, bs1);
        __syncthreads();

#pragma unroll
        for (int ks = 0; ks < 2; ++ks) {           // two k-steps of 16
            const int kk = ks * 16 + fk;
            bf16x8 af[2], bfr[2];
#pragma unroll
            for (int t = 0; t < 2; ++t)
                af[t] = *(const bf16x8*)&As[wm + t * 32 + fl][kk];
#pragma unroll
            for (int t = 0; t < 2; ++t)
                bfr[t] = *(const bf16x8*)&Bs[wn + t * 32 + fl][kk];
#pragma unroll
            for (int mt = 0; mt < 2; ++mt)
#pragma unroll
                for (int nt = 0; nt < 2; ++nt)
                    acc[mt][nt] = __builtin_amdgcn_mfma_f32_32x32x16_bf16(
                        af[mt], bfr[nt], acc[mt][nt], 0, 0, 0);
        }
        __syncthreads();
    }

    // epilogue: C/D layout col = lane&31, row = (reg&3) + 8*(reg>>2) + 4*(lane>>5)
#pragma unroll
    for (int mt = 0; mt < 2; ++mt) {
        const int row_base = bm + wm + mt * 32 + 4 * (lane >> 5);
#pragma unroll
        for (int nt = 0; nt < 2; ++nt) {
            const int col = bn + wn + nt * 32 + fl;
            const float bv = bias[col];
            float* cp = C + (size_t)row_base * N + col;
#pragma unroll
            for (int reg = 0; reg < 16; ++reg) {
                const int roff = (reg & 3) + 8 * (reg >> 2);
                cp[(size_t)roff * N] = acc[mt][nt][reg] + bv;
            }
        }
    }
}

extern "C" void kernel_launch(void* const* d_in, const int* in_sizes, int n_in,
                              void* d_out, int out_size, void* d_ws, size_t ws_size,
                              hipStream_t stream) {
    const float* x    = (const float*)d_in[0];   // (4096,1024,4) fp32
    const float* w    = (const float*)d_in[1];   // (1024,1024,4) fp32
    const float* bias = (const float*)d_in[2];   // (1024,4) fp32
    float* out = (float*)d_out;                  // (4096,1024,4) fp32

    __bf16* Abf  = (__bf16*)d_ws;                                   // 32 MB
    __bf16* Wbig = (__bf16*)((char*)d_ws + (size_t)M * K * 2);      // 32 MB

    prep_kernel<<<CVT_BLOCKS + EXP_BLOCKS, 256, 0, stream>>>(x, w, Abf, Wbig);

    dim3 grid(N / BN, M / BM);  // 32 x 32
    qgemm_kernel<<<grid, 256, 0, stream>>>(Abf, Wbig, bias, out);
}